// Round 6
// baseline (10634.482 us; speedup 1.0000x reference)
//
#include <hip/hip_runtime.h>
#include <stdint.h>

typedef __attribute__((ext_vector_type(4))) int   i32x4;
typedef __attribute__((ext_vector_type(4))) float f32x4;
typedef __attribute__((ext_vector_type(8))) short bf16x8;
typedef unsigned short u16;
typedef unsigned char  u8;

#define QMAX 32512.0f
#define ZSCL 2047.0f
#define INV_ZSCL (1.0f/2047.0f)

__device__ __forceinline__ float bf2f(u16 u) {
    union { uint32_t i; float f; } v; v.i = ((uint32_t)u) << 16; return v.f;
}
__device__ __forceinline__ u16 f2bf(float f) {
    union { float f; uint32_t i; } v; v.f = f;
    uint32_t r = v.i + 0x7fffu + ((v.i >> 16) & 1u);
    return (u16)(r >> 16);
}
__device__ __forceinline__ float sigf(float x) { return 1.0f / (1.0f + __expf(-x)); }
__device__ __forceinline__ i32x4 mfma8(i32x4 a, i32x4 b, i32x4 c) {
    return __builtin_amdgcn_mfma_i32_16x16x64_i8(a, b, c, 0, 0, 0);
}
__device__ __forceinline__ f32x4 mfmabf(bf16x8 a, bf16x8 b, f32x4 c) {
    return __builtin_amdgcn_mfma_f32_16x16x32_bf16(a, b, c, 0, 0, 0);
}
__device__ __forceinline__ void qsplit(float v, float s, int& hi, int& lo) {
    float q = fminf(fmaxf(v * s, -QMAX), QMAX);
    int qi = (int)rintf(q);
    lo = ((qi + 128) & 255) - 128;
    hi = (qi - lo) >> 8;
}
__device__ __forceinline__ void gll16(const void* g, void* l) {
    __builtin_amdgcn_global_load_lds(
        (const __attribute__((address_space(1))) void*)g,
        (__attribute__((address_space(3))) void*)l, 16, 0, 0);
}
// lgkm-only barrier: LDS producer/consumer sync WITHOUT draining vmcnt
__device__ __forceinline__ void bar_lgk() {
    __builtin_amdgcn_sched_barrier(0);
    asm volatile("s_waitcnt lgkmcnt(0)" ::: "memory");
    __builtin_amdgcn_s_barrier();
    __builtin_amdgcn_sched_barrier(0);
}

// ---------------- per-column max |U|
__global__ __launch_bounds__(256) void uscale_kernel(
    const float* __restrict__ U0, const float* __restrict__ U1,
    const float* __restrict__ U2, const float* __restrict__ U3,
    float* __restrict__ Uscale)
{
    int idx = blockIdx.x * 256 + threadIdx.x;
    if (idx < 4096) {
        int l = idx >> 10, col = idx & 1023;
        const float* U = (l==0)?U0:(l==1)?U1:(l==2)?U2:U3;
        float m = 0.f;
        for (int k = 0; k < 256; ++k) m = fmaxf(m, fabsf(U[k*1024 + col]));
        Uscale[idx] = m;
    }
}

// ---------------- pack U to i8 hi/lo, COLSPLIT-SLICE layout:
// Upk4[lstm][j 4][g 4][a 4][kt 4][half 2][lane 64][16B]  (128KB per (lstm,j))
// col = g*256 + j*64 + a*16 + (lane&15); k = kt*64 + (lane>>4)*16 + i
__global__ __launch_bounds__(256) void upack_kernel(
    const float* __restrict__ U0, const float* __restrict__ U1,
    const float* __restrict__ U2, const float* __restrict__ U3,
    const float* __restrict__ Uscale, u8* __restrict__ Upk4)
{
    int idx = blockIdx.x * 256 + threadIdx.x;      // one u32 per thread, < 524288
    int byte = idx * 4;
    int lst = byte >> 19;  int off = byte & 0x7FFFF;
    int j = off >> 17;     int g = (off >> 15) & 3;
    int a = (off >> 13) & 3; int kt = (off >> 11) & 3;
    int half = (off >> 10) & 1;
    int lane = (off >> 4) & 63;
    int i0 = off & 15;
    const float* U = (lst==0)?U0:(lst==1)?U1:(lst==2)?U2:U3;
    int col = g*256 + j*64 + a*16 + (lane & 15);
    float s = QMAX / fmaxf(Uscale[lst*1024 + col], 1e-30f);
    uint32_t wd = 0;
    for (int jj = 0; jj < 4; ++jj) {
        int k = kt*64 + (lane >> 4)*16 + i0 + jj;
        int hi, lo; qsplit(U[k*1024 + col], s, hi, lo);
        int b = half ? lo : hi;
        wd |= ((uint32_t)(b & 255)) << (8*jj);
    }
    ((uint32_t*)Upk4)[idx] = wd;
}

// ---------------- W -> bf16 pair (hi + residual), [lstm][col][96], zero-padded k>=F
__global__ __launch_bounds__(256) void wpair_kernel(
    const float* __restrict__ W0, const float* __restrict__ W1,
    const float* __restrict__ W2, const float* __restrict__ W3,
    u16* __restrict__ Wbh, u16* __restrict__ Wbl)
{
    int idx = blockIdx.x * 256 + threadIdx.x;      // < 393216
    int lstm = idx / 98304; int rem = idx - lstm*98304;
    int col = rem / 96; int k = rem - col*96;
    const int F = (lstm==0)?80:(lstm==1)?64:(lstm==2)?48:32;
    const float* W = (lstm==0)?W0:(lstm==1)?W1:(lstm==2)?W2:W3;
    float v = (k < F) ? W[k*1024 + col] : 0.f;
    u16 hb = f2bf(v);
    Wbh[idx] = hb;
    Wbl[idx] = f2bf(v - bf2f(hb));
}

// ---------------- z_x GEMM -> i16 packed (R4/R5-verbatim)
__global__ __launch_bounds__(512) void zx_gemm_kernel(
    const float* __restrict__ x0, const float* __restrict__ x1,
    const float* __restrict__ x2, const float* __restrict__ x3,
    const float* __restrict__ bb0, const float* __restrict__ bb1,
    const float* __restrict__ bb2, const float* __restrict__ bb3,
    const u16* __restrict__ Wbh, const u16* __restrict__ Wbl,
    short* __restrict__ zxg, u8* __restrict__ maskb, int t0, int nt)
{
    const int lstm = blockIdx.x >> 7;
    const int b = blockIdx.x & 127;
    const int F = (lstm==0)?80:(lstm==1)?64:(lstm==2)?48:32;
    const int KT = (F + 31) >> 5;
    const float* xin  = (lstm==0)?x0:(lstm==1)?x1:(lstm==2)?x2:x3;
    const float* bias = (lstm==0)?bb0:(lstm==1)?bb1:(lstm==2)?bb2:bb3;

    const int tid = threadIdx.x;
    const int w = tid >> 6, l = tid & 63, lg = l >> 4, ln = l & 15;
    const int rr = tid >> 5, cc = tid & 31;

    __shared__ u16 xh[16][104], xl[16][104];
    __shared__ u8 anyf[16][32];

    float bv[8];
    size_t wo_base[8];
#pragma unroll
    for (int ti = 0; ti < 8; ++ti) {
        int g = ti >> 1, m = ti & 1;
        int col = (g*16 + 2*w + m)*16 + ln;
        bv[ti] = bias[col];
        wo_base[ti] = ((size_t)(lstm*1024) + col)*96 + lg*8;
    }

    const int TT = nt >> 4;
    for (int tt = 0; tt < TT; ++tt) {
        const int tb = t0 + tt*16;
        bool any = false;
#pragma unroll
        for (int jx = 0; jx < 3; ++jx) {
            int f = cc + 32*jx;
            float v = (f < F) ? xin[((size_t)b*256 + tb + rr)*F + f] : 0.f;
            if (f < F) any = any || (v != -1.0f);
            u16 hb = f2bf(v);
            xh[rr][f] = hb;
            xl[rr][f] = f2bf(v - bf2f(hb));
        }
        anyf[rr][cc] = any ? 1 : 0;
        __syncthreads();
        if (tid < 16) {
            int mm = 0;
#pragma unroll
            for (int q = 0; q < 32; ++q) mm |= anyf[tid][q];
            maskb[((size_t)(lstm*128 + b))*256 + tb + tid] = (u8)(mm ? 1 : 0);
        }

        f32x4 acc[8];
#pragma unroll
        for (int ti = 0; ti < 8; ++ti) acc[ti] = (f32x4){0.f,0.f,0.f,0.f};

        for (int kt = 0; kt < KT; ++kt) {
            bf16x8 ah = *(const bf16x8*)&xh[ln][kt*32 + lg*8];
            bf16x8 al = *(const bf16x8*)&xl[ln][kt*32 + lg*8];
#pragma unroll
            for (int ti = 0; ti < 8; ++ti) {
                bf16x8 wh = *(const bf16x8*)(Wbh + wo_base[ti] + kt*32);
                bf16x8 wl = *(const bf16x8*)(Wbl + wo_base[ti] + kt*32);
                acc[ti] = mfmabf(ah, wh, acc[ti]);
                acc[ti] = mfmabf(al, wh, acc[ti]);
                acc[ti] = mfmabf(ah, wl, acc[ti]);
            }
        }
#pragma unroll
        for (int reg = 0; reg < 4; ++reg) {
            int tl = tt*16 + lg*4 + reg;
            uint32_t d[4];
#pragma unroll
            for (int g = 0; g < 4; ++g) {
                int q0 = (int)rintf(fminf(fmaxf((acc[2*g  ][reg] + bv[2*g  ]) * ZSCL, -32767.f), 32767.f));
                int q1 = (int)rintf(fminf(fmaxf((acc[2*g+1][reg] + bv[2*g+1]) * ZSCL, -32767.f), 32767.f));
                d[g] = ((uint32_t)q0 & 0xffffu) | (((uint32_t)q1 & 0xffffu) << 16);
            }
            i32x4 out = { (int)d[0], (int)d[1], (int)d[2], (int)d[3] };
            short* dst = zxg + ((size_t)(lstm*128 + b)*nt + tl)*1024 + (w*16 + ln)*8;
            *(i32x4*)dst = out;
        }
        __syncthreads();
    }
}

// ---------------- zero the arrival counters (before each rec launch)
__global__ void zero_cnt_kernel(int* __restrict__ cnt) {
    if (threadIdx.x < 32) cnt[threadIdx.x] = 0;
}

// ---------------- recurrence: col-split x4, U-slice LDS-resident, h exchanged via L2
// grid 128: bx&7 -> xcd {lstm = xcd>>1, rb parity}; bx>>3 -> {j = slot>>2, rb}.
__global__ __launch_bounds__(512) void lstm_rec_kernel(
    const u8* __restrict__ Upk4, const short* __restrict__ zxg,
    const u8* __restrict__ maskb, const float* __restrict__ Uscale,
    float* __restrict__ c_state, float* __restrict__ h_state,
    u16* __restrict__ merged, u8* __restrict__ exbuf, int* __restrict__ cnt,
    int t0, int nt)
{
    const int bx = blockIdx.x;
    const int xcd = bx & 7;
    const int lstm = xcd >> 1;
    const int slot = bx >> 3;
    const int j = slot >> 2;                       // col-split partner id 0..3
    const int rb = ((slot & 3) << 1) | (xcd & 1);  // row-block 0..7
    const int b0 = rb * 16;

    const int tid = threadIdx.x;
    const int w = tid >> 6, l = tid & 63, lg = l >> 4, ln = l & 15;

    __shared__ __align__(16) u8 ulds[131072];      // U slice (hi/lo), resident
    __shared__ __align__(16) u8 qA[2][16][256];    // h quantized, swizzled
    __shared__ float z_lds[4][16][64];             // gate partials exchange
    __shared__ u8 mask_l[16][256];
    __shared__ float rmf[4][16];                   // per-slice per-row quant scale

    // ---- U slice -> LDS (once) + mask
    const u8* ubase = Upk4 + (size_t)(lstm*4 + j) * 131072;
#pragma unroll
    for (int it = 0; it < 16; ++it)
        gll16(ubase + it*8192 + tid*16, &ulds[it*8192 + tid*16]);
    for (int i = tid; i < 4096; i += 512) {
        int r = i >> 8, s = i & 255;
        mask_l[r][s] = (s < nt) ? maskb[((size_t)(lstm*128 + b0 + r))*256 + t0 + s] : (u8)1;
    }
    __syncthreads();   // full drain once (init)

    // writer-side (MFMA) mapping: wave w -> unit-subblock a, gate-pair gp
    const int a = w & 3, gp = w >> 2;
    float cUw[2];
#pragma unroll
    for (int ti = 0; ti < 2; ++ti) {
        int g = gp*2 + ti;
        int col = g*256 + j*64 + a*16 + ln;
        cUw[ti] = Uscale[lstm*1024 + col] * (1.0f/(QMAX*QMAX));
    }

    // epilogue/state mapping: thread (w,l) -> row r_e, units K0=64j+ul, K1=K0+16
    const int r_e = w + 8*(l >> 5);
    const int ul  = 32*((l >> 4) & 1) + (l & 15);
    const int K0 = 64*j + ul, K1 = K0 + 16;
    const int p0 = (((K0 >> 4) ^ r_e) << 4) | (K0 & 15);
    const int p1 = (((K1 >> 4) ^ r_e) << 4) | (K1 & 15);

    float c_[2], h_[2];
    if (t0 == 0) { c_[0]=c_[1]=h_[0]=h_[1]=0.f; }
    else {
        size_t o = ((size_t)(lstm*128 + b0 + r_e))*256;
        c_[0] = c_state[o + K0]; c_[1] = c_state[o + K1];
        h_[0] = h_state[o + K0]; h_[1] = h_state[o + K1];
    }

    const int wprime = 2*j + ((l >> 4) & 1);
    const short* zx_base = zxg + ((size_t)(lstm*128 + b0 + r_e))*nt*1024 + (wprime*16 + (l & 15))*8;
    u8* exgrp = exbuf + (size_t)(lstm*8 + rb)*32768;
    int* cnt_p = cnt + (lstm*8 + rb);
    u16* mg_base = merged + (((size_t)(b0 + r_e)*256) + t0)*1024 + lstm*256;

    i32x4 zA = *(const i32x4*)(zx_base);

    for (int s = 0; s < nt; ++s) {
        // ---- (1) quantize own h slice (per-row slice max via 32-lane reduce)
        float rm = fmaxf(h_[0], h_[1]);
        rm = fmaxf(rm, __shfl_xor(rm, 1));
        rm = fmaxf(rm, __shfl_xor(rm, 2));
        rm = fmaxf(rm, __shfl_xor(rm, 4));
        rm = fmaxf(rm, __shfl_xor(rm, 8));
        rm = fmaxf(rm, __shfl_xor(rm, 16));
        float qs = QMAX / fmaxf(rm, 1e-30f);
        int h0, l0, h1, l1;
        qsplit(h_[0], qs, h0, l0);
        qsplit(h_[1], qs, h1, l1);
        u8* exmy = exgrp + (s & 1)*16384 + j*4096;
        exmy[       r_e*64 + ul     ] = (u8)h0;
        exmy[       r_e*64 + ul + 16] = (u8)h1;
        exmy[1024 + r_e*64 + ul     ] = (u8)l0;
        exmy[1024 + r_e*64 + ul + 16] = (u8)l1;
        if ((l & 31) == 0) {
            *(float*)(exmy + 2048 + r_e*4) = rm;
            rmf[j][r_e] = rm;
        }
        qA[0][r_e][p0] = (u8)h0;  qA[0][r_e][p1] = (u8)h1;
        qA[1][r_e][p0] = (u8)l0;  qA[1][r_e][p1] = (u8)l1;

        // ---- (2) publish + arrive + poll + acquire
        __threadfence();
        __syncthreads();
        if (tid == 0)
            __hip_atomic_fetch_add(cnt_p, 1, __ATOMIC_RELAXED, __HIP_MEMORY_SCOPE_AGENT);
        // prefetch zx(s+1) while waiting
        i32x4 zn;
        { int sn = (s + 1 < nt) ? (s + 1) : s;
          zn = *(const i32x4*)(zx_base + (size_t)sn*1024); }
        const int tgt = 4*(s + 1);
        while (__hip_atomic_load(cnt_p, __ATOMIC_RELAXED, __HIP_MEMORY_SCOPE_AGENT) < tgt)
            __builtin_amdgcn_s_sleep(1);
        __threadfence();

        // ---- (3) gather foreign slices -> qA / rmf
        const u8* exb = exgrp + (s & 1)*16384;
        if (tid < 384) {
            int jj = tid >> 7; int jsrc = jj + (jj >= j ? 1 : 0);
            int half = (tid >> 6) & 1, rr2 = (tid >> 2) & 15, m = tid & 3;
            i32x4 v = *(const i32x4*)(exb + jsrc*4096 + half*1024 + rr2*64 + m*16);
            int pos = (((4*jsrc + m) ^ rr2) << 4);
            *(i32x4*)&qA[half][rr2][pos] = v;
        } else if (tid < 432) {
            int q = tid - 384; int jj = q >> 4; int jsrc = jj + (jj >= j ? 1 : 0);
            int rr2 = q & 15;
            rmf[jsrc][rr2] = *(const float*)(exb + jsrc*4096 + 2048 + rr2*4);
        }
        bar_lgk();   // qA + rmf ready

        // ---- (4) h @ U-slice: 24 MFMAs, per-kt accumulators
        i32x4 aP[2][4], aX[2][4];
#pragma unroll
        for (int ti = 0; ti < 2; ++ti)
#pragma unroll
            for (int kt = 0; kt < 4; ++kt) { aP[ti][kt] = (i32x4){0,0,0,0}; aX[ti][kt] = (i32x4){0,0,0,0}; }
#pragma unroll
        for (int kt = 0; kt < 4; ++kt) {
            int slt = (((kt*4 + lg) ^ ln)) * 16;
            i32x4 hh = *(const i32x4*)&qA[0][ln][slt];
            i32x4 hl = *(const i32x4*)&qA[1][ln][slt];
#pragma unroll
            for (int ti = 0; ti < 2; ++ti) {
                int g = gp*2 + ti;
                const u8* bp = &ulds[(size_t)(((g*4 + a)*4 + kt)*2048) + l*16];
                i32x4 bh = *(const i32x4*)bp;
                i32x4 bl = *(const i32x4*)(bp + 1024);
                aP[ti][kt] = mfma8(hh, bh, aP[ti][kt]);
                aX[ti][kt] = mfma8(hl, bh, aX[ti][kt]);
                aX[ti][kt] = mfma8(hh, bl, aX[ti][kt]);
            }
        }
        // dequant (per-kt slice scale) -> z_lds
        float4 rv[4];
#pragma unroll
        for (int kt = 0; kt < 4; ++kt) rv[kt] = *(const float4*)&rmf[kt][lg*4];
#pragma unroll
        for (int ti = 0; ti < 2; ++ti) {
            int g = gp*2 + ti;
#pragma unroll
            for (int reg = 0; reg < 4; ++reg) {
                int row = lg*4 + reg;
                float zs = 0.f;
#pragma unroll
                for (int kt = 0; kt < 4; ++kt)
                    zs += (65536.f*(float)aP[ti][kt][reg] + 256.f*(float)aX[ti][kt][reg])
                          * ((const float*)&rv[kt])[reg];
                z_lds[g][row][a*16 + ln] = zs * cUw[ti];
            }
        }
        bar_lgk();   // z_lds ready

        // ---- (5) epilogue: gates for own (row, 2 units)
        const int mk = mask_l[r_e][s];
        float zg4[4][2];
#pragma unroll
        for (int g = 0; g < 4; ++g) {
            zg4[g][0] = z_lds[g][r_e][ul];
            zg4[g][1] = z_lds[g][r_e][ul + 16];
        }
        u16* mgs = mg_base + (size_t)s*1024;
#pragma unroll
        for (int m = 0; m < 2; ++m) {
            float zi = (float)(short)(m ? ((uint32_t)zA[0] >> 16) : ((uint32_t)zA[0] & 0xffffu))*INV_ZSCL + zg4[0][m];
            float zf = (float)(short)(m ? ((uint32_t)zA[1] >> 16) : ((uint32_t)zA[1] & 0xffffu))*INV_ZSCL + zg4[1][m];
            float zg = (float)(short)(m ? ((uint32_t)zA[2] >> 16) : ((uint32_t)zA[2] & 0xffffu))*INV_ZSCL + zg4[2][m];
            float zo = (float)(short)(m ? ((uint32_t)zA[3] >> 16) : ((uint32_t)zA[3] & 0xffffu))*INV_ZSCL + zg4[3][m];
            float ig = sigf(zi), fg = sigf(zf), og = sigf(zo);
            float gg = fmaxf(zg, 0.f);
            float cn = fg * c_[m] + ig * gg;
            float hn = og * fmaxf(cn, 0.f);
            if (!mk) { cn = c_[m]; hn = h_[m]; }
            c_[m] = cn; h_[m] = hn;
            mgs[m ? K1 : K0] = f2bf(hn);
        }
        zA = zn;
    }

    if (t0 + nt < 256) {
        size_t o = ((size_t)(lstm*128 + b0 + r_e))*256;
        c_state[o + K0] = c_[0]; c_state[o + K1] = c_[1];
        h_state[o + K0] = h_[0]; h_state[o + K1] = h_[1];
    }
}

// ---------------- attention + output head (verbatim)
__global__ __launch_bounds__(256) void attn_kernel(
    const u16* __restrict__ merged,
    const float* __restrict__ w_att, const float* __restrict__ b_att,
    const float* __restrict__ w_out, const float* __restrict__ b_out,
    float* __restrict__ out)
{
    const int b = blockIdx.x;
    const int tid = threadIdx.x;
    const int wv = tid >> 6;
    const int l = tid & 63;

    __shared__ float watt_s[1024];
    __shared__ float wout_s[1024];
    __shared__ float sc[256];
    __shared__ float red[8];

    for (int i = tid; i < 1024; i += 256) {
        watt_s[i] = w_att[i];
        wout_s[i] = w_out[i];
    }
    __syncthreads();

    const float batt = b_att[0];

    for (int tt = wv; tt < 256; tt += 4) {
        const u16* row = merged + ((size_t)b * 256 + tt) * 1024 + l * 16;
        uint4 q0 = *(const uint4*)(row);
        uint4 q1 = *(const uint4*)(row + 8);
        const float* wp = &watt_s[l * 16];
        uint32_t qa[8] = {q0.x, q0.y, q0.z, q0.w, q1.x, q1.y, q1.z, q1.w};
        float s = 0.f;
#pragma unroll
        for (int i = 0; i < 8; ++i) {
            s += bf2f((u16)(qa[i] & 0xffffu)) * wp[2 * i];
            s += bf2f((u16)(qa[i] >> 16)) * wp[2 * i + 1];
        }
#pragma unroll
        for (int o = 32; o > 0; o >>= 1) s += __shfl_xor(s, o);
        if (l == 0) sc[tt] = tanhf(s + batt);
    }
    __syncthreads();

    float v = sc[tid];
    float mx = v;
#pragma unroll
    for (int o = 32; o > 0; o >>= 1) mx = fmaxf(mx, __shfl_xor(mx, o));
    if (l == 0) red[wv] = mx;
    __syncthreads();
    mx = fmaxf(fmaxf(red[0], red[1]), fmaxf(red[2], red[3]));
    float p = __expf(v - mx);
    float sm = p;
#pragma unroll
    for (int o = 32; o > 0; o >>= 1) sm += __shfl_xor(sm, o);
    if (l == 0) red[4 + wv] = sm;
    __syncthreads();
    sm = red[4] + red[5] + red[6] + red[7];
    p /= sm;
    sc[tid] = p;
    __syncthreads();

    const int d0 = tid * 4;
    float a0 = 0.f, a1 = 0.f, a2 = 0.f, a3 = 0.f;
    for (int t = 0; t < 256; ++t) {
        float pp = sc[t];
        const u16* mp = merged + ((size_t)b * 256 + t) * 1024 + d0;
        ushort4 q = *(const ushort4*)mp;
        a0 += pp * bf2f(q.x);
        a1 += pp * bf2f(q.y);
        a2 += pp * bf2f(q.z);
        a3 += pp * bf2f(q.w);
    }
    float part = a0 * wout_s[d0] + a1 * wout_s[d0 + 1] + a2 * wout_s[d0 + 2] + a3 * wout_s[d0 + 3];
#pragma unroll
    for (int o = 32; o > 0; o >>= 1) part += __shfl_xor(part, o);
    __syncthreads();
    if (l == 0) red[wv] = part;
    __syncthreads();
    if (tid == 0) {
        float tot = red[0] + red[1] + red[2] + red[3] + b_out[0];
        out[b] = 1.0f / (1.0f + __expf(-tot));
    }
}

extern "C" void kernel_launch(void* const* d_in, const int* in_sizes, int n_in,
                              void* d_out, int out_size, void* d_ws, size_t ws_size,
                              hipStream_t stream) {
    (void)in_sizes; (void)n_in; (void)out_size;
    const float* x[4]; const float* W[4]; const float* U[4]; const float* bb[4];
    for (int i = 0; i < 4; ++i) {
        x[i]  = (const float*)d_in[4 * i + 0];
        W[i]  = (const float*)d_in[4 * i + 1];
        U[i]  = (const float*)d_in[4 * i + 2];
        bb[i] = (const float*)d_in[4 * i + 3];
    }
    const float* w_att = (const float*)d_in[16];
    const float* b_att = (const float*)d_in[17];
    const float* w_out = (const float*)d_in[18];
    const float* b_out = (const float*)d_in[19];

    u8* base = (u8*)d_ws;
    size_t off = 0;
    auto alloc = [&](size_t n) { u8* p = base + off; off += (n + 255) & ~(size_t)255; return p; };
    u16*   merged  = (u16*)  alloc(67108864);        // [128][256][1024] bf16
    u8*    Upk4    =         alloc(2097152);         // i8 hi/lo, colsplit-slice layout
    u16*   Wbh     = (u16*)  alloc(786432);
    u16*   Wbl     = (u16*)  alloc(786432);
    float* Uscale  = (float*)alloc(16384);
    u8*    maskb   =         alloc(131072);
    float* c_state = (float*)alloc(524288);
    float* h_state = (float*)alloc(524288);
    u8*    exbuf   =         alloc(1048576);         // 32 groups x 2 bufs x 4 x 4KB
    int*   cnt     = (int*)  alloc(128);
    size_t fixed = off;

    int nt = 256;                                     // zx chunk = nt MB; adapt to ws_size
    while (nt > 16 && fixed + (size_t)nt * 1048576 > ws_size) nt >>= 1;
    short* zxg = (short*)alloc((size_t)nt * 1048576);

    uscale_kernel<<<dim3(16),   dim3(256), 0, stream>>>(U[0], U[1], U[2], U[3], Uscale);
    upack_kernel <<<dim3(2048), dim3(256), 0, stream>>>(U[0], U[1], U[2], U[3], Uscale, Upk4);
    wpair_kernel <<<dim3(1536), dim3(256), 0, stream>>>(W[0], W[1], W[2], W[3], Wbh, Wbl);

    for (int t0 = 0; t0 < 256; t0 += nt) {
        zx_gemm_kernel<<<dim3(512), dim3(512), 0, stream>>>(
            x[0], x[1], x[2], x[3], bb[0], bb[1], bb[2], bb[3],
            Wbh, Wbl, zxg, maskb, t0, nt);
        zero_cnt_kernel<<<dim3(1), dim3(64), 0, stream>>>(cnt);
        lstm_rec_kernel<<<dim3(128), dim3(512), 0, stream>>>(
            Upk4, zxg, maskb, Uscale, c_state, h_state, merged, exbuf, cnt, t0, nt);
    }

    attn_kernel<<<dim3(128), dim3(256), 0, stream>>>(
        merged, w_att, b_att, w_out, b_out, (float*)d_out);
}

// Round 7
// 10172.730 us; speedup vs baseline: 1.0454x; 1.0454x over previous
//
#include <hip/hip_runtime.h>
#include <stdint.h>

typedef __attribute__((ext_vector_type(4))) int   i32x4;
typedef __attribute__((ext_vector_type(4))) float f32x4;
typedef __attribute__((ext_vector_type(8))) short bf16x8;
typedef unsigned short u16;
typedef unsigned char  u8;

#define QMAX 32512.0f
#define ZSCL 2047.0f
#define INV_ZSCL (1.0f/2047.0f)

__device__ __forceinline__ float bf2f(u16 u) {
    union { uint32_t i; float f; } v; v.i = ((uint32_t)u) << 16; return v.f;
}
__device__ __forceinline__ u16 f2bf(float f) {
    union { float f; uint32_t i; } v; v.f = f;
    uint32_t r = v.i + 0x7fffu + ((v.i >> 16) & 1u);
    return (u16)(r >> 16);
}
__device__ __forceinline__ float sigf(float x) { return 1.0f / (1.0f + __expf(-x)); }
__device__ __forceinline__ i32x4 mfma8(i32x4 a, i32x4 b, i32x4 c) {
    return __builtin_amdgcn_mfma_i32_16x16x64_i8(a, b, c, 0, 0, 0);
}
__device__ __forceinline__ f32x4 mfmabf(bf16x8 a, bf16x8 b, f32x4 c) {
    return __builtin_amdgcn_mfma_f32_16x16x32_bf16(a, b, c, 0, 0, 0);
}
__device__ __forceinline__ void qsplit(float v, float s, int& hi, int& lo) {
    float q = fminf(fmaxf(v * s, -QMAX), QMAX);
    int qi = (int)rintf(q);
    lo = ((qi + 128) & 255) - 128;
    hi = (qi - lo) >> 8;
}
__device__ __forceinline__ void gll16(const void* g, void* l) {
    __builtin_amdgcn_global_load_lds(
        (const __attribute__((address_space(1))) void*)g,
        (__attribute__((address_space(3))) void*)l, 16, 0, 0);
}
// lgkm-only barrier: LDS producer/consumer sync WITHOUT draining vmcnt
__device__ __forceinline__ void bar_lgk() {
    __builtin_amdgcn_sched_barrier(0);
    asm volatile("s_waitcnt lgkmcnt(0)" ::: "memory");
    __builtin_amdgcn_s_barrier();
    __builtin_amdgcn_sched_barrier(0);
}

// ---------------- per-column max |U|
__global__ __launch_bounds__(256) void uscale_kernel(
    const float* __restrict__ U0, const float* __restrict__ U1,
    const float* __restrict__ U2, const float* __restrict__ U3,
    float* __restrict__ Uscale)
{
    int idx = blockIdx.x * 256 + threadIdx.x;
    if (idx < 4096) {
        int l = idx >> 10, col = idx & 1023;
        const float* U = (l==0)?U0:(l==1)?U1:(l==2)?U2:U3;
        float m = 0.f;
        for (int k = 0; k < 256; ++k) m = fmaxf(m, fabsf(U[k*1024 + col]));
        Uscale[idx] = m;
    }
}

// ---------------- pack U to i8 hi/lo, COLSPLIT-SLICE layout (R6 verbatim):
// Upk4[lstm][j 4][g 4][a 4][kt 4][half 2][lane 64][16B]  (128KB per (lstm,j))
// col = g*256 + j*64 + a*16 + (lane&15); k = kt*64 + (lane>>4)*16 + i
__global__ __launch_bounds__(256) void upack_kernel(
    const float* __restrict__ U0, const float* __restrict__ U1,
    const float* __restrict__ U2, const float* __restrict__ U3,
    const float* __restrict__ Uscale, u8* __restrict__ Upk4)
{
    int idx = blockIdx.x * 256 + threadIdx.x;      // one u32 per thread, < 524288
    int byte = idx * 4;
    int lst = byte >> 19;  int off = byte & 0x7FFFF;
    int j = off >> 17;     int g = (off >> 15) & 3;
    int a = (off >> 13) & 3; int kt = (off >> 11) & 3;
    int half = (off >> 10) & 1;
    int lane = (off >> 4) & 63;
    int i0 = off & 15;
    const float* U = (lst==0)?U0:(lst==1)?U1:(lst==2)?U2:U3;
    int col = g*256 + j*64 + a*16 + (lane & 15);
    float s = QMAX / fmaxf(Uscale[lst*1024 + col], 1e-30f);
    uint32_t wd = 0;
    for (int jj = 0; jj < 4; ++jj) {
        int k = kt*64 + (lane >> 4)*16 + i0 + jj;
        int hi, lo; qsplit(U[k*1024 + col], s, hi, lo);
        int b = half ? lo : hi;
        wd |= ((uint32_t)(b & 255)) << (8*jj);
    }
    ((uint32_t*)Upk4)[idx] = wd;
}

// ---------------- W -> bf16 pair (hi + residual), [lstm][col][96], zero-padded k>=F
__global__ __launch_bounds__(256) void wpair_kernel(
    const float* __restrict__ W0, const float* __restrict__ W1,
    const float* __restrict__ W2, const float* __restrict__ W3,
    u16* __restrict__ Wbh, u16* __restrict__ Wbl)
{
    int idx = blockIdx.x * 256 + threadIdx.x;      // < 393216
    int lstm = idx / 98304; int rem = idx - lstm*98304;
    int col = rem / 96; int k = rem - col*96;
    const int F = (lstm==0)?80:(lstm==1)?64:(lstm==2)?48:32;
    const float* W = (lstm==0)?W0:(lstm==1)?W1:(lstm==2)?W2:W3;
    float v = (k < F) ? W[k*1024 + col] : 0.f;
    u16 hb = f2bf(v);
    Wbh[idx] = hb;
    Wbl[idx] = f2bf(v - bf2f(hb));
}

// ---------------- z_x GEMM -> i16 packed (R4/R5-verbatim)
__global__ __launch_bounds__(512) void zx_gemm_kernel(
    const float* __restrict__ x0, const float* __restrict__ x1,
    const float* __restrict__ x2, const float* __restrict__ x3,
    const float* __restrict__ bb0, const float* __restrict__ bb1,
    const float* __restrict__ bb2, const float* __restrict__ bb3,
    const u16* __restrict__ Wbh, const u16* __restrict__ Wbl,
    short* __restrict__ zxg, u8* __restrict__ maskb, int t0, int nt)
{
    const int lstm = blockIdx.x >> 7;
    const int b = blockIdx.x & 127;
    const int F = (lstm==0)?80:(lstm==1)?64:(lstm==2)?48:32;
    const int KT = (F + 31) >> 5;
    const float* xin  = (lstm==0)?x0:(lstm==1)?x1:(lstm==2)?x2:x3;
    const float* bias = (lstm==0)?bb0:(lstm==1)?bb1:(lstm==2)?bb2:bb3;

    const int tid = threadIdx.x;
    const int w = tid >> 6, l = tid & 63, lg = l >> 4, ln = l & 15;
    const int rr = tid >> 5, cc = tid & 31;

    __shared__ u16 xh[16][104], xl[16][104];
    __shared__ u8 anyf[16][32];

    float bv[8];
    size_t wo_base[8];
#pragma unroll
    for (int ti = 0; ti < 8; ++ti) {
        int g = ti >> 1, m = ti & 1;
        int col = (g*16 + 2*w + m)*16 + ln;
        bv[ti] = bias[col];
        wo_base[ti] = ((size_t)(lstm*1024) + col)*96 + lg*8;
    }

    const int TT = nt >> 4;
    for (int tt = 0; tt < TT; ++tt) {
        const int tb = t0 + tt*16;
        bool any = false;
#pragma unroll
        for (int jx = 0; jx < 3; ++jx) {
            int f = cc + 32*jx;
            float v = (f < F) ? xin[((size_t)b*256 + tb + rr)*F + f] : 0.f;
            if (f < F) any = any || (v != -1.0f);
            u16 hb = f2bf(v);
            xh[rr][f] = hb;
            xl[rr][f] = f2bf(v - bf2f(hb));
        }
        anyf[rr][cc] = any ? 1 : 0;
        __syncthreads();
        if (tid < 16) {
            int mm = 0;
#pragma unroll
            for (int q = 0; q < 32; ++q) mm |= anyf[tid][q];
            maskb[((size_t)(lstm*128 + b))*256 + tb + tid] = (u8)(mm ? 1 : 0);
        }

        f32x4 acc[8];
#pragma unroll
        for (int ti = 0; ti < 8; ++ti) acc[ti] = (f32x4){0.f,0.f,0.f,0.f};

        for (int kt = 0; kt < KT; ++kt) {
            bf16x8 ah = *(const bf16x8*)&xh[ln][kt*32 + lg*8];
            bf16x8 al = *(const bf16x8*)&xl[ln][kt*32 + lg*8];
#pragma unroll
            for (int ti = 0; ti < 8; ++ti) {
                bf16x8 wh = *(const bf16x8*)(Wbh + wo_base[ti] + kt*32);
                bf16x8 wl = *(const bf16x8*)(Wbl + wo_base[ti] + kt*32);
                acc[ti] = mfmabf(ah, wh, acc[ti]);
                acc[ti] = mfmabf(al, wh, acc[ti]);
                acc[ti] = mfmabf(ah, wl, acc[ti]);
            }
        }
#pragma unroll
        for (int reg = 0; reg < 4; ++reg) {
            int tl = tt*16 + lg*4 + reg;
            uint32_t d[4];
#pragma unroll
            for (int g = 0; g < 4; ++g) {
                int q0 = (int)rintf(fminf(fmaxf((acc[2*g  ][reg] + bv[2*g  ]) * ZSCL, -32767.f), 32767.f));
                int q1 = (int)rintf(fminf(fmaxf((acc[2*g+1][reg] + bv[2*g+1]) * ZSCL, -32767.f), 32767.f));
                d[g] = ((uint32_t)q0 & 0xffffu) | (((uint32_t)q1 & 0xffffu) << 16);
            }
            i32x4 out = { (int)d[0], (int)d[1], (int)d[2], (int)d[3] };
            short* dst = zxg + ((size_t)(lstm*128 + b)*nt + tl)*1024 + (w*16 + ln)*8;
            *(i32x4*)dst = out;
        }
        __syncthreads();
    }
}

// ---------------- zero the arrival counters (before each rec launch)
__global__ void zero_cnt_kernel(int* __restrict__ cnt) {
    if (threadIdx.x < 32) cnt[threadIdx.x] = 0;
}

// ---------------- recurrence: col-split x4, U-slice LDS-resident, h exchanged via L2
// grid 128: bx&7 -> xcd {lstm = xcd>>1, rb parity}; bx>>3 -> {j = slot>>2, rb}.
// R7 changes vs R6: single-lane arrive+poll (kills the 65k-thread poll storm),
// padded z_lds (4-way -> 2-way bank conflicts). Everything else verbatim.
__global__ __launch_bounds__(512) void lstm_rec_kernel(
    const u8* __restrict__ Upk4, const short* __restrict__ zxg,
    const u8* __restrict__ maskb, const float* __restrict__ Uscale,
    float* __restrict__ c_state, float* __restrict__ h_state,
    u16* __restrict__ merged, u8* __restrict__ exbuf, int* __restrict__ cnt,
    int t0, int nt)
{
    const int bx = blockIdx.x;
    const int xcd = bx & 7;
    const int lstm = xcd >> 1;
    const int slot = bx >> 3;
    const int j = slot >> 2;                       // col-split partner id 0..3
    const int rb = ((slot & 3) << 1) | (xcd & 1);  // row-block 0..7
    const int b0 = rb * 16;

    const int tid = threadIdx.x;
    const int w = tid >> 6, l = tid & 63, lg = l >> 4, ln = l & 15;

    __shared__ __align__(16) u8 ulds[131072];      // U slice (hi/lo), resident
    __shared__ __align__(16) u8 qA[2][16][256];    // h quantized, swizzled
    __shared__ float z_lds[4][16][68];             // gate partials (+4 pad: 2-way max)
    __shared__ u8 mask_l[16][256];
    __shared__ float rmf[4][16];                   // per-slice per-row quant scale

    // ---- U slice -> LDS (once) + mask
    const u8* ubase = Upk4 + (size_t)(lstm*4 + j) * 131072;
#pragma unroll
    for (int it = 0; it < 16; ++it)
        gll16(ubase + it*8192 + tid*16, &ulds[it*8192 + tid*16]);
    for (int i = tid; i < 4096; i += 512) {
        int r = i >> 8, s = i & 255;
        mask_l[r][s] = (s < nt) ? maskb[((size_t)(lstm*128 + b0 + r))*256 + t0 + s] : (u8)1;
    }
    __syncthreads();   // full drain once (init)

    // writer-side (MFMA) mapping: wave w -> unit-subblock a, gate-pair gp
    const int a = w & 3, gp = w >> 2;
    float cUw[2];
#pragma unroll
    for (int ti = 0; ti < 2; ++ti) {
        int g = gp*2 + ti;
        int col = g*256 + j*64 + a*16 + ln;
        cUw[ti] = Uscale[lstm*1024 + col] * (1.0f/(QMAX*QMAX));
    }

    // epilogue/state mapping: thread (w,l) -> row r_e, units K0=64j+ul, K1=K0+16
    const int r_e = w + 8*(l >> 5);
    const int ul  = 32*((l >> 4) & 1) + (l & 15);
    const int K0 = 64*j + ul, K1 = K0 + 16;
    const int p0 = (((K0 >> 4) ^ r_e) << 4) | (K0 & 15);
    const int p1 = (((K1 >> 4) ^ r_e) << 4) | (K1 & 15);

    float c_[2], h_[2];
    if (t0 == 0) { c_[0]=c_[1]=h_[0]=h_[1]=0.f; }
    else {
        size_t o = ((size_t)(lstm*128 + b0 + r_e))*256;
        c_[0] = c_state[o + K0]; c_[1] = c_state[o + K1];
        h_[0] = h_state[o + K0]; h_[1] = h_state[o + K1];
    }

    const int wprime = 2*j + ((l >> 4) & 1);
    const short* zx_base = zxg + ((size_t)(lstm*128 + b0 + r_e))*nt*1024 + (wprime*16 + (l & 15))*8;
    u8* exgrp = exbuf + (size_t)(lstm*8 + rb)*32768;
    int* cnt_p = cnt + (lstm*8 + rb);
    u16* mg_base = merged + (((size_t)(b0 + r_e)*256) + t0)*1024 + lstm*256;

    i32x4 zA = *(const i32x4*)(zx_base);

    for (int s = 0; s < nt; ++s) {
        // ---- (1) quantize own h slice (per-row slice max via 32-lane reduce)
        float rm = fmaxf(h_[0], h_[1]);
        rm = fmaxf(rm, __shfl_xor(rm, 1));
        rm = fmaxf(rm, __shfl_xor(rm, 2));
        rm = fmaxf(rm, __shfl_xor(rm, 4));
        rm = fmaxf(rm, __shfl_xor(rm, 8));
        rm = fmaxf(rm, __shfl_xor(rm, 16));
        float qs = QMAX / fmaxf(rm, 1e-30f);
        int h0, l0, h1, l1;
        qsplit(h_[0], qs, h0, l0);
        qsplit(h_[1], qs, h1, l1);
        u8* exmy = exgrp + (s & 1)*16384 + j*4096;
        exmy[       r_e*64 + ul     ] = (u8)h0;
        exmy[       r_e*64 + ul + 16] = (u8)h1;
        exmy[1024 + r_e*64 + ul     ] = (u8)l0;
        exmy[1024 + r_e*64 + ul + 16] = (u8)l1;
        if ((l & 31) == 0) {
            *(float*)(exmy + 2048 + r_e*4) = rm;
            rmf[j][r_e] = rm;
        }
        qA[0][r_e][p0] = (u8)h0;  qA[0][r_e][p1] = (u8)h1;
        qA[1][r_e][p0] = (u8)l0;  qA[1][r_e][p1] = (u8)l1;

        // prefetch zx(s+1) before the wait (overlaps partner skew)
        i32x4 zn;
        { int sn = (s + 1 < nt) ? (s + 1) : s;
          zn = *(const i32x4*)(zx_base + (size_t)sn*1024); }

        // ---- (2) publish(release) + single-lane arrive/poll + acquire
        __threadfence();                 // release: publish stores -> L2, ordered
        __syncthreads();                 // all threads' fences complete
        if (tid == 0) {
            __hip_atomic_fetch_add(cnt_p, 1, __ATOMIC_RELAXED, __HIP_MEMORY_SCOPE_AGENT);
            const int tgt = 4*(s + 1);
            while (__hip_atomic_load(cnt_p, __ATOMIC_RELAXED, __HIP_MEMORY_SCOPE_AGENT) < tgt)
                __builtin_amdgcn_s_sleep(1);
        }
        __syncthreads();                 // broadcast "partners arrived"
        __threadfence();                 // acquire: invalidate L1 before gather

        // ---- (3) gather foreign slices -> qA / rmf
        const u8* exb = exgrp + (s & 1)*16384;
        if (tid < 384) {
            int jj = tid >> 7; int jsrc = jj + (jj >= j ? 1 : 0);
            int half = (tid >> 6) & 1, rr2 = (tid >> 2) & 15, m = tid & 3;
            i32x4 v = *(const i32x4*)(exb + jsrc*4096 + half*1024 + rr2*64 + m*16);
            int pos = (((4*jsrc + m) ^ rr2) << 4);
            *(i32x4*)&qA[half][rr2][pos] = v;
        } else if (tid < 432) {
            int q = tid - 384; int jj = q >> 4; int jsrc = jj + (jj >= j ? 1 : 0);
            int rr2 = q & 15;
            rmf[jsrc][rr2] = *(const float*)(exb + jsrc*4096 + 2048 + rr2*4);
        }
        bar_lgk();   // qA + rmf ready

        // ---- (4) h @ U-slice: 24 MFMAs, per-kt accumulators
        i32x4 aP[2][4], aX[2][4];
#pragma unroll
        for (int ti = 0; ti < 2; ++ti)
#pragma unroll
            for (int kt = 0; kt < 4; ++kt) { aP[ti][kt] = (i32x4){0,0,0,0}; aX[ti][kt] = (i32x4){0,0,0,0}; }
#pragma unroll
        for (int kt = 0; kt < 4; ++kt) {
            int slt = (((kt*4 + lg) ^ ln)) * 16;
            i32x4 hh = *(const i32x4*)&qA[0][ln][slt];
            i32x4 hl = *(const i32x4*)&qA[1][ln][slt];
#pragma unroll
            for (int ti = 0; ti < 2; ++ti) {
                int g = gp*2 + ti;
                const u8* bp = &ulds[(size_t)(((g*4 + a)*4 + kt)*2048) + l*16];
                i32x4 bh = *(const i32x4*)bp;
                i32x4 bl = *(const i32x4*)(bp + 1024);
                aP[ti][kt] = mfma8(hh, bh, aP[ti][kt]);
                aX[ti][kt] = mfma8(hl, bh, aX[ti][kt]);
                aX[ti][kt] = mfma8(hh, bl, aX[ti][kt]);
            }
        }
        // dequant (per-kt slice scale) -> z_lds
        float4 rv[4];
#pragma unroll
        for (int kt = 0; kt < 4; ++kt) rv[kt] = *(const float4*)&rmf[kt][lg*4];
#pragma unroll
        for (int ti = 0; ti < 2; ++ti) {
            int g = gp*2 + ti;
#pragma unroll
            for (int reg = 0; reg < 4; ++reg) {
                int row = lg*4 + reg;
                float zs = 0.f;
#pragma unroll
                for (int kt = 0; kt < 4; ++kt)
                    zs += (65536.f*(float)aP[ti][kt][reg] + 256.f*(float)aX[ti][kt][reg])
                          * ((const float*)&rv[kt])[reg];
                z_lds[g][row][a*16 + ln] = zs * cUw[ti];
            }
        }
        bar_lgk();   // z_lds ready

        // ---- (5) epilogue: gates for own (row, 2 units)
        const int mk = mask_l[r_e][s];
        float zg4[4][2];
#pragma unroll
        for (int g = 0; g < 4; ++g) {
            zg4[g][0] = z_lds[g][r_e][ul];
            zg4[g][1] = z_lds[g][r_e][ul + 16];
        }
        u16* mgs = mg_base + (size_t)s*1024;
#pragma unroll
        for (int m = 0; m < 2; ++m) {
            float zi = (float)(short)(m ? ((uint32_t)zA[0] >> 16) : ((uint32_t)zA[0] & 0xffffu))*INV_ZSCL + zg4[0][m];
            float zf = (float)(short)(m ? ((uint32_t)zA[1] >> 16) : ((uint32_t)zA[1] & 0xffffu))*INV_ZSCL + zg4[1][m];
            float zg = (float)(short)(m ? ((uint32_t)zA[2] >> 16) : ((uint32_t)zA[2] & 0xffffu))*INV_ZSCL + zg4[2][m];
            float zo = (float)(short)(m ? ((uint32_t)zA[3] >> 16) : ((uint32_t)zA[3] & 0xffffu))*INV_ZSCL + zg4[3][m];
            float ig = sigf(zi), fg = sigf(zf), og = sigf(zo);
            float gg = fmaxf(zg, 0.f);
            float cn = fg * c_[m] + ig * gg;
            float hn = og * fmaxf(cn, 0.f);
            if (!mk) { cn = c_[m]; hn = h_[m]; }
            c_[m] = cn; h_[m] = hn;
            mgs[m ? K1 : K0] = f2bf(hn);
        }
        zA = zn;
    }

    if (t0 + nt < 256) {
        size_t o = ((size_t)(lstm*128 + b0 + r_e))*256;
        c_state[o + K0] = c_[0]; c_state[o + K1] = c_[1];
        h_state[o + K0] = h_[0]; h_state[o + K1] = h_[1];
    }
}

// ---------------- attention + output head (verbatim)
__global__ __launch_bounds__(256) void attn_kernel(
    const u16* __restrict__ merged,
    const float* __restrict__ w_att, const float* __restrict__ b_att,
    const float* __restrict__ w_out, const float* __restrict__ b_out,
    float* __restrict__ out)
{
    const int b = blockIdx.x;
    const int tid = threadIdx.x;
    const int wv = tid >> 6;
    const int l = tid & 63;

    __shared__ float watt_s[1024];
    __shared__ float wout_s[1024];
    __shared__ float sc[256];
    __shared__ float red[8];

    for (int i = tid; i < 1024; i += 256) {
        watt_s[i] = w_att[i];
        wout_s[i] = w_out[i];
    }
    __syncthreads();

    const float batt = b_att[0];

    for (int tt = wv; tt < 256; tt += 4) {
        const u16* row = merged + ((size_t)b * 256 + tt) * 1024 + l * 16;
        uint4 q0 = *(const uint4*)(row);
        uint4 q1 = *(const uint4*)(row + 8);
        const float* wp = &watt_s[l * 16];
        uint32_t qa[8] = {q0.x, q0.y, q0.z, q0.w, q1.x, q1.y, q1.z, q1.w};
        float s = 0.f;
#pragma unroll
        for (int i = 0; i < 8; ++i) {
            s += bf2f((u16)(qa[i] & 0xffffu)) * wp[2 * i];
            s += bf2f((u16)(qa[i] >> 16)) * wp[2 * i + 1];
        }
#pragma unroll
        for (int o = 32; o > 0; o >>= 1) s += __shfl_xor(s, o);
        if (l == 0) sc[tt] = tanhf(s + batt);
    }
    __syncthreads();

    float v = sc[tid];
    float mx = v;
#pragma unroll
    for (int o = 32; o > 0; o >>= 1) mx = fmaxf(mx, __shfl_xor(mx, o));
    if (l == 0) red[wv] = mx;
    __syncthreads();
    mx = fmaxf(fmaxf(red[0], red[1]), fmaxf(red[2], red[3]));
    float p = __expf(v - mx);
    float sm = p;
#pragma unroll
    for (int o = 32; o > 0; o >>= 1) sm += __shfl_xor(sm, o);
    if (l == 0) red[4 + wv] = sm;
    __syncthreads();
    sm = red[4] + red[5] + red[6] + red[7];
    p /= sm;
    sc[tid] = p;
    __syncthreads();

    const int d0 = tid * 4;
    float a0 = 0.f, a1 = 0.f, a2 = 0.f, a3 = 0.f;
    for (int t = 0; t < 256; ++t) {
        float pp = sc[t];
        const u16* mp = merged + ((size_t)b * 256 + t) * 1024 + d0;
        ushort4 q = *(const ushort4*)mp;
        a0 += pp * bf2f(q.x);
        a1 += pp * bf2f(q.y);
        a2 += pp * bf2f(q.z);
        a3 += pp * bf2f(q.w);
    }
    float part = a0 * wout_s[d0] + a1 * wout_s[d0 + 1] + a2 * wout_s[d0 + 2] + a3 * wout_s[d0 + 3];
#pragma unroll
    for (int o = 32; o > 0; o >>= 1) part += __shfl_xor(part, o);
    __syncthreads();
    if (l == 0) red[wv] = part;
    __syncthreads();
    if (tid == 0) {
        float tot = red[0] + red[1] + red[2] + red[3] + b_out[0];
        out[b] = 1.0f / (1.0f + __expf(-tot));
    }
}

extern "C" void kernel_launch(void* const* d_in, const int* in_sizes, int n_in,
                              void* d_out, int out_size, void* d_ws, size_t ws_size,
                              hipStream_t stream) {
    (void)in_sizes; (void)n_in; (void)out_size;
    const float* x[4]; const float* W[4]; const float* U[4]; const float* bb[4];
    for (int i = 0; i < 4; ++i) {
        x[i]  = (const float*)d_in[4 * i + 0];
        W[i]  = (const float*)d_in[4 * i + 1];
        U[i]  = (const float*)d_in[4 * i + 2];
        bb[i] = (const float*)d_in[4 * i + 3];
    }
    const float* w_att = (const float*)d_in[16];
    const float* b_att = (const float*)d_in[17];
    const float* w_out = (const float*)d_in[18];
    const float* b_out = (const float*)d_in[19];

    u8* base = (u8*)d_ws;
    size_t off = 0;
    auto alloc = [&](size_t n) { u8* p = base + off; off += (n + 255) & ~(size_t)255; return p; };
    u16*   merged  = (u16*)  alloc(67108864);        // [128][256][1024] bf16
    u8*    Upk4    =         alloc(2097152);         // i8 hi/lo, colsplit-slice layout
    u16*   Wbh     = (u16*)  alloc(786432);
    u16*   Wbl     = (u16*)  alloc(786432);
    float* Uscale  = (float*)alloc(16384);
    u8*    maskb   =         alloc(131072);
    float* c_state = (float*)alloc(524288);
    float* h_state = (float*)alloc(524288);
    u8*    exbuf   =         alloc(1048576);         // 32 groups x 2 bufs x 4 x 4KB
    int*   cnt     = (int*)  alloc(128);
    size_t fixed = off;

    int nt = 256;                                     // zx chunk = nt MB; adapt to ws_size
    while (nt > 16 && fixed + (size_t)nt * 1048576 > ws_size) nt >>= 1;
    short* zxg = (short*)alloc((size_t)nt * 1048576);

    uscale_kernel<<<dim3(16),   dim3(256), 0, stream>>>(U[0], U[1], U[2], U[3], Uscale);
    upack_kernel <<<dim3(2048), dim3(256), 0, stream>>>(U[0], U[1], U[2], U[3], Uscale, Upk4);
    wpair_kernel <<<dim3(1536), dim3(256), 0, stream>>>(W[0], W[1], W[2], W[3], Wbh, Wbl);

    for (int t0 = 0; t0 < 256; t0 += nt) {
        zx_gemm_kernel<<<dim3(512), dim3(512), 0, stream>>>(
            x[0], x[1], x[2], x[3], bb[0], bb[1], bb[2], bb[3],
            Wbh, Wbl, zxg, maskb, t0, nt);
        zero_cnt_kernel<<<dim3(1), dim3(64), 0, stream>>>(cnt);
        lstm_rec_kernel<<<dim3(128), dim3(512), 0, stream>>>(
            Upk4, zxg, maskb, Uscale, c_state, h_state, merged, exbuf, cnt, t0, nt);
    }

    attn_kernel<<<dim3(128), dim3(256), 0, stream>>>(
        merged, w_att, b_att, w_out, b_out, (float*)d_out);
}

// Round 8
// 1133.936 us; speedup vs baseline: 9.3784x; 8.9712x over previous
//
#include <hip/hip_runtime.h>
#include <stdint.h>

typedef __attribute__((ext_vector_type(4))) int   i32x4;
typedef __attribute__((ext_vector_type(4))) float f32x4;
typedef __attribute__((ext_vector_type(8))) short bf16x8;
typedef unsigned short u16;
typedef unsigned char  u8;

#define QMAX 32512.0f
#define ZSCL 2047.0f
#define INV_ZSCL (1.0f/2047.0f)

__device__ __forceinline__ float bf2f(u16 u) {
    union { uint32_t i; float f; } v; v.i = ((uint32_t)u) << 16; return v.f;
}
__device__ __forceinline__ u16 f2bf(float f) {
    union { float f; uint32_t i; } v; v.f = f;
    uint32_t r = v.i + 0x7fffu + ((v.i >> 16) & 1u);
    return (u16)(r >> 16);
}
__device__ __forceinline__ float sigf(float x) { return 1.0f / (1.0f + __expf(-x)); }
__device__ __forceinline__ i32x4 mfma8(i32x4 a, i32x4 b, i32x4 c) {
    return __builtin_amdgcn_mfma_i32_16x16x64_i8(a, b, c, 0, 0, 0);
}
__device__ __forceinline__ f32x4 mfmabf(bf16x8 a, bf16x8 b, f32x4 c) {
    return __builtin_amdgcn_mfma_f32_16x16x32_bf16(a, b, c, 0, 0, 0);
}
__device__ __forceinline__ void qsplit(float v, float s, int& hi, int& lo) {
    float q = fminf(fmaxf(v * s, -QMAX), QMAX);
    int qi = (int)rintf(q);
    lo = ((qi + 128) & 255) - 128;
    hi = (qi - lo) >> 8;
}
__device__ __forceinline__ void gll16(const void* g, void* l) {
    __builtin_amdgcn_global_load_lds(
        (const __attribute__((address_space(1))) void*)g,
        (__attribute__((address_space(3))) void*)l, 16, 0, 0);
}
// lgkm-only barrier: LDS producer/consumer sync WITHOUT draining vmcnt
__device__ __forceinline__ void bar_lgk() {
    __builtin_amdgcn_sched_barrier(0);
    asm volatile("s_waitcnt lgkmcnt(0)" ::: "memory");
    __builtin_amdgcn_s_barrier();
    __builtin_amdgcn_sched_barrier(0);
}
// MALL-coherent (agent-scope, relaxed) accesses — per-instruction coherence,
// NO cache-flushing fences. These bypass the non-coherent per-XCD L2s.
__device__ __forceinline__ void mall_store_u32(uint32_t* p, uint32_t v) {
    __hip_atomic_store(p, v, __ATOMIC_RELAXED, __HIP_MEMORY_SCOPE_AGENT);
}
__device__ __forceinline__ uint32_t mall_load_u32(const uint32_t* p) {
    return __hip_atomic_load(p, __ATOMIC_RELAXED, __HIP_MEMORY_SCOPE_AGENT);
}
__device__ __forceinline__ void mall_store_f32(float* p, float v) {
    __hip_atomic_store(p, v, __ATOMIC_RELAXED, __HIP_MEMORY_SCOPE_AGENT);
}
__device__ __forceinline__ float mall_load_f32(const float* p) {
    return __hip_atomic_load(p, __ATOMIC_RELAXED, __HIP_MEMORY_SCOPE_AGENT);
}

// ---------------- per-column max |U|
__global__ __launch_bounds__(256) void uscale_kernel(
    const float* __restrict__ U0, const float* __restrict__ U1,
    const float* __restrict__ U2, const float* __restrict__ U3,
    float* __restrict__ Uscale)
{
    int idx = blockIdx.x * 256 + threadIdx.x;
    if (idx < 4096) {
        int l = idx >> 10, col = idx & 1023;
        const float* U = (l==0)?U0:(l==1)?U1:(l==2)?U2:U3;
        float m = 0.f;
        for (int k = 0; k < 256; ++k) m = fmaxf(m, fabsf(U[k*1024 + col]));
        Uscale[idx] = m;
    }
}

// ---------------- pack U to i8 hi/lo, COLSPLIT-SLICE layout (R6/R7 verbatim):
// Upk4[lstm][j 4][g 4][a 4][kt 4][half 2][lane 64][16B]  (128KB per (lstm,j))
// col = g*256 + j*64 + a*16 + (lane&15); k = kt*64 + (lane>>4)*16 + i
__global__ __launch_bounds__(256) void upack_kernel(
    const float* __restrict__ U0, const float* __restrict__ U1,
    const float* __restrict__ U2, const float* __restrict__ U3,
    const float* __restrict__ Uscale, u8* __restrict__ Upk4)
{
    int idx = blockIdx.x * 256 + threadIdx.x;      // one u32 per thread, < 524288
    int byte = idx * 4;
    int lst = byte >> 19;  int off = byte & 0x7FFFF;
    int j = off >> 17;     int g = (off >> 15) & 3;
    int a = (off >> 13) & 3; int kt = (off >> 11) & 3;
    int half = (off >> 10) & 1;
    int lane = (off >> 4) & 63;
    int i0 = off & 15;
    const float* U = (lst==0)?U0:(lst==1)?U1:(lst==2)?U2:U3;
    int col = g*256 + j*64 + a*16 + (lane & 15);
    float s = QMAX / fmaxf(Uscale[lst*1024 + col], 1e-30f);
    uint32_t wd = 0;
    for (int jj = 0; jj < 4; ++jj) {
        int k = kt*64 + (lane >> 4)*16 + i0 + jj;
        int hi, lo; qsplit(U[k*1024 + col], s, hi, lo);
        int b = half ? lo : hi;
        wd |= ((uint32_t)(b & 255)) << (8*jj);
    }
    ((uint32_t*)Upk4)[idx] = wd;
}

// ---------------- W -> bf16 pair (hi + residual), [lstm][col][96], zero-padded k>=F
__global__ __launch_bounds__(256) void wpair_kernel(
    const float* __restrict__ W0, const float* __restrict__ W1,
    const float* __restrict__ W2, const float* __restrict__ W3,
    u16* __restrict__ Wbh, u16* __restrict__ Wbl)
{
    int idx = blockIdx.x * 256 + threadIdx.x;      // < 393216
    int lstm = idx / 98304; int rem = idx - lstm*98304;
    int col = rem / 96; int k = rem - col*96;
    const int F = (lstm==0)?80:(lstm==1)?64:(lstm==2)?48:32;
    const float* W = (lstm==0)?W0:(lstm==1)?W1:(lstm==2)?W2:W3;
    float v = (k < F) ? W[k*1024 + col] : 0.f;
    u16 hb = f2bf(v);
    Wbh[idx] = hb;
    Wbl[idx] = f2bf(v - bf2f(hb));
}

// ---------------- z_x GEMM -> i16 packed (R4-R7 verbatim)
__global__ __launch_bounds__(512) void zx_gemm_kernel(
    const float* __restrict__ x0, const float* __restrict__ x1,
    const float* __restrict__ x2, const float* __restrict__ x3,
    const float* __restrict__ bb0, const float* __restrict__ bb1,
    const float* __restrict__ bb2, const float* __restrict__ bb3,
    const u16* __restrict__ Wbh, const u16* __restrict__ Wbl,
    short* __restrict__ zxg, u8* __restrict__ maskb, int t0, int nt)
{
    const int lstm = blockIdx.x >> 7;
    const int b = blockIdx.x & 127;
    const int F = (lstm==0)?80:(lstm==1)?64:(lstm==2)?48:32;
    const int KT = (F + 31) >> 5;
    const float* xin  = (lstm==0)?x0:(lstm==1)?x1:(lstm==2)?x2:x3;
    const float* bias = (lstm==0)?bb0:(lstm==1)?bb1:(lstm==2)?bb2:bb3;

    const int tid = threadIdx.x;
    const int w = tid >> 6, l = tid & 63, lg = l >> 4, ln = l & 15;
    const int rr = tid >> 5, cc = tid & 31;

    __shared__ u16 xh[16][104], xl[16][104];
    __shared__ u8 anyf[16][32];

    float bv[8];
    size_t wo_base[8];
#pragma unroll
    for (int ti = 0; ti < 8; ++ti) {
        int g = ti >> 1, m = ti & 1;
        int col = (g*16 + 2*w + m)*16 + ln;
        bv[ti] = bias[col];
        wo_base[ti] = ((size_t)(lstm*1024) + col)*96 + lg*8;
    }

    const int TT = nt >> 4;
    for (int tt = 0; tt < TT; ++tt) {
        const int tb = t0 + tt*16;
        bool any = false;
#pragma unroll
        for (int jx = 0; jx < 3; ++jx) {
            int f = cc + 32*jx;
            float v = (f < F) ? xin[((size_t)b*256 + tb + rr)*F + f] : 0.f;
            if (f < F) any = any || (v != -1.0f);
            u16 hb = f2bf(v);
            xh[rr][f] = hb;
            xl[rr][f] = f2bf(v - bf2f(hb));
        }
        anyf[rr][cc] = any ? 1 : 0;
        __syncthreads();
        if (tid < 16) {
            int mm = 0;
#pragma unroll
            for (int q = 0; q < 32; ++q) mm |= anyf[tid][q];
            maskb[((size_t)(lstm*128 + b))*256 + tb + tid] = (u8)(mm ? 1 : 0);
        }

        f32x4 acc[8];
#pragma unroll
        for (int ti = 0; ti < 8; ++ti) acc[ti] = (f32x4){0.f,0.f,0.f,0.f};

        for (int kt = 0; kt < KT; ++kt) {
            bf16x8 ah = *(const bf16x8*)&xh[ln][kt*32 + lg*8];
            bf16x8 al = *(const bf16x8*)&xl[ln][kt*32 + lg*8];
#pragma unroll
            for (int ti = 0; ti < 8; ++ti) {
                bf16x8 wh = *(const bf16x8*)(Wbh + wo_base[ti] + kt*32);
                bf16x8 wl = *(const bf16x8*)(Wbl + wo_base[ti] + kt*32);
                acc[ti] = mfmabf(ah, wh, acc[ti]);
                acc[ti] = mfmabf(al, wh, acc[ti]);
                acc[ti] = mfmabf(ah, wl, acc[ti]);
            }
        }
#pragma unroll
        for (int reg = 0; reg < 4; ++reg) {
            int tl = tt*16 + lg*4 + reg;
            uint32_t d[4];
#pragma unroll
            for (int g = 0; g < 4; ++g) {
                int q0 = (int)rintf(fminf(fmaxf((acc[2*g  ][reg] + bv[2*g  ]) * ZSCL, -32767.f), 32767.f));
                int q1 = (int)rintf(fminf(fmaxf((acc[2*g+1][reg] + bv[2*g+1]) * ZSCL, -32767.f), 32767.f));
                d[g] = ((uint32_t)q0 & 0xffffu) | (((uint32_t)q1 & 0xffffu) << 16);
            }
            i32x4 out = { (int)d[0], (int)d[1], (int)d[2], (int)d[3] };
            short* dst = zxg + ((size_t)(lstm*128 + b)*nt + tl)*1024 + (w*16 + ln)*8;
            *(i32x4*)dst = out;
        }
        __syncthreads();
    }
}

// ---------------- zero the arrival counters (128B-strided, before each rec launch)
__global__ void zero_cnt_kernel(int* __restrict__ cnt) {
    if (threadIdx.x < 32) cnt[threadIdx.x * 32] = 0;
}

// ---------------- recurrence: col-split x4, U-slice LDS-resident, h exchanged via
// MALL-coherent atomics (NO threadfence -> no L2 flush). grid 128.
// exbuf layout per group (32KB): buf(2) x [j(4) x {words u32[16][32] @0, rm f32[16] @2048}]
__global__ __launch_bounds__(512) void lstm_rec_kernel(
    const u8* __restrict__ Upk4, const short* __restrict__ zxg,
    const u8* __restrict__ maskb, const float* __restrict__ Uscale,
    float* __restrict__ c_state, float* __restrict__ h_state,
    u16* __restrict__ merged, u8* __restrict__ exbuf, int* __restrict__ cnt,
    int t0, int nt)
{
    const int bx = blockIdx.x;
    const int xcd = bx & 7;
    const int lstm = xcd >> 1;
    const int slot = bx >> 3;
    const int j = slot >> 2;                       // col-split partner id 0..3
    const int rb = ((slot & 3) << 1) | (xcd & 1);  // row-block 0..7
    const int b0 = rb * 16;

    const int tid = threadIdx.x;
    const int w = tid >> 6, l = tid & 63, lg = l >> 4, ln = l & 15;

    __shared__ __align__(16) u8 ulds[131072];      // U slice (hi/lo), resident
    __shared__ __align__(16) u8 qA[2][16][256];    // h quantized, swizzled
    __shared__ float z_lds[4][16][68];             // gate partials (+4 pad)
    __shared__ u8 mask_l[16][256];
    __shared__ float rmf[4][16];                   // per-slice per-row quant scale

    // ---- U slice -> LDS (once) + mask
    const u8* ubase = Upk4 + (size_t)(lstm*4 + j) * 131072;
#pragma unroll
    for (int it = 0; it < 16; ++it)
        gll16(ubase + it*8192 + tid*16, &ulds[it*8192 + tid*16]);
    for (int i = tid; i < 4096; i += 512) {
        int r = i >> 8, s = i & 255;
        mask_l[r][s] = (s < nt) ? maskb[((size_t)(lstm*128 + b0 + r))*256 + t0 + s] : (u8)1;
    }
    __syncthreads();   // full drain once (init)

    // writer-side (MFMA) mapping: wave w -> unit-subblock a, gate-pair gp
    const int a = w & 3, gp = w >> 2;
    float cUw[2];
#pragma unroll
    for (int ti = 0; ti < 2; ++ti) {
        int g = gp*2 + ti;
        int col = g*256 + j*64 + a*16 + ln;
        cUw[ti] = Uscale[lstm*1024 + col] * (1.0f/(QMAX*QMAX));
    }

    // epilogue/state mapping: thread (w,l) -> row r_e, units K0=64j+ul, K1=K0+16
    const int r_e = w + 8*(l >> 5);
    const int ul  = 32*((l >> 4) & 1) + (l & 15);
    const int K0 = 64*j + ul, K1 = K0 + 16;
    const int p0 = (((K0 >> 4) ^ r_e) << 4) | (K0 & 15);
    const int p1 = (((K1 >> 4) ^ r_e) << 4) | (K1 & 15);

    float c_[2], h_[2];
    if (t0 == 0) { c_[0]=c_[1]=h_[0]=h_[1]=0.f; }
    else {
        size_t o = ((size_t)(lstm*128 + b0 + r_e))*256;
        c_[0] = c_state[o + K0]; c_[1] = c_state[o + K1];
        h_[0] = h_state[o + K0]; h_[1] = h_state[o + K1];
    }

    const int wprime = 2*j + ((l >> 4) & 1);
    const short* zx_base = zxg + ((size_t)(lstm*128 + b0 + r_e))*nt*1024 + (wprime*16 + (l & 15))*8;
    const int group = lstm*8 + rb;
    u8* exgrp = exbuf + (size_t)group*32768;
    int* cnt_p = cnt + group*32;                   // 128B-strided counters
    u16* mg_base = merged + (((size_t)(b0 + r_e)*256) + t0)*1024 + lstm*256;

    // foreign partner ids (fixed)
    const int js0 = (j == 0) ? 1 : 0;
    const int js1 = (j <= 1) ? 2 : 1;
    const int js2 = (j <= 2) ? 3 : 2;

    i32x4 zA = *(const i32x4*)(zx_base);

    for (int s = 0; s < nt; ++s) {
        const int buf = s & 1;
        u8* exb = exgrp + buf*16384;

        // ---- (1) quantize own h slice (per-row slice max via 32-lane reduce)
        float rm = fmaxf(h_[0], h_[1]);
        rm = fmaxf(rm, __shfl_xor(rm, 1));
        rm = fmaxf(rm, __shfl_xor(rm, 2));
        rm = fmaxf(rm, __shfl_xor(rm, 4));
        rm = fmaxf(rm, __shfl_xor(rm, 8));
        rm = fmaxf(rm, __shfl_xor(rm, 16));
        float qs = QMAX / fmaxf(rm, 1e-30f);
        int h0, l0, h1, l1;
        qsplit(h_[0], qs, h0, l0);
        qsplit(h_[1], qs, h1, l1);

        // own bytes into qA (LDS)
        qA[0][r_e][p0] = (u8)h0;  qA[0][r_e][p1] = (u8)h1;
        qA[1][r_e][p0] = (u8)l0;  qA[1][r_e][p1] = (u8)l1;

        // publish own word + rm via MALL-coherent stores (no fence!)
        uint32_t wmy = ((uint32_t)(u8)h0) | (((uint32_t)(u8)h1) << 8)
                     | (((uint32_t)(u8)l0) << 16) | (((uint32_t)(u8)l1) << 24);
        mall_store_u32((uint32_t*)(exb + j*4096) + (r_e*32 + (l & 31)), wmy);
        if ((l & 31) == 0) {
            mall_store_f32((float*)(exb + j*4096 + 2048) + r_e, rm);
            rmf[j][r_e] = rm;
        }

        // prefetch zx(s+1) (ordinary cached load; drains at the barrier)
        i32x4 zn;
        { int sn = (s + 1 < nt) ? (s + 1) : s;
          zn = *(const i32x4*)(zx_base + (size_t)sn*1024); }

        // ---- (2) drain(syncthreads) + single-lane arrive/poll + broadcast
        __syncthreads();                 // vmcnt(0) drain: publishes are at MALL
        if (tid == 0) {
            __hip_atomic_fetch_add(cnt_p, 1, __ATOMIC_RELAXED, __HIP_MEMORY_SCOPE_AGENT);
            const int tgt = 4*(s + 1);
            while (__hip_atomic_load(cnt_p, __ATOMIC_RELAXED, __HIP_MEMORY_SCOPE_AGENT) < tgt)
                __builtin_amdgcn_s_sleep(1);
        }
        __syncthreads();                 // broadcast "all partners arrived"

        // ---- (3) gather foreign slices via MALL loads -> qA / rmf
        {
            const int row = tid >> 5, idx = tid & 31;
            const uint32_t* s0 = (const uint32_t*)(exb + js0*4096) + (row*32 + idx);
            const uint32_t* s1 = (const uint32_t*)(exb + js1*4096) + (row*32 + idx);
            const uint32_t* s2 = (const uint32_t*)(exb + js2*4096) + (row*32 + idx);
            uint32_t w0 = mall_load_u32(s0);
            uint32_t w1 = mall_load_u32(s1);
            uint32_t w2 = mall_load_u32(s2);
            const int uu = (idx & 15) | ((idx & 16) << 1);   // ul from idx
#pragma unroll
            for (int f = 0; f < 3; ++f) {
                int jsrc = (f == 0) ? js0 : (f == 1) ? js1 : js2;
                uint32_t ww = (f == 0) ? w0 : (f == 1) ? w1 : w2;
                int Ka = 64*jsrc + uu, Kb = Ka + 16;
                int pa = (((Ka >> 4) ^ row) << 4) | (Ka & 15);
                int pb = (((Kb >> 4) ^ row) << 4) | (Kb & 15);
                qA[0][row][pa] = (u8)(ww & 255);
                qA[0][row][pb] = (u8)((ww >> 8) & 255);
                qA[1][row][pa] = (u8)((ww >> 16) & 255);
                qA[1][row][pb] = (u8)(ww >> 24);
            }
            if (tid < 48) {
                int f = tid >> 4, rr2 = tid & 15;
                int jsrc = (f == 0) ? js0 : (f == 1) ? js1 : js2;
                rmf[jsrc][rr2] = mall_load_f32((const float*)(exb + jsrc*4096 + 2048) + rr2);
            }
        }
        bar_lgk();   // qA + rmf ready

        // ---- (4) h @ U-slice: 24 MFMAs, per-kt accumulators (R7 verbatim)
        i32x4 aP[2][4], aX[2][4];
#pragma unroll
        for (int ti = 0; ti < 2; ++ti)
#pragma unroll
            for (int kt = 0; kt < 4; ++kt) { aP[ti][kt] = (i32x4){0,0,0,0}; aX[ti][kt] = (i32x4){0,0,0,0}; }
#pragma unroll
        for (int kt = 0; kt < 4; ++kt) {
            int slt = (((kt*4 + lg) ^ ln)) * 16;
            i32x4 hh = *(const i32x4*)&qA[0][ln][slt];
            i32x4 hl = *(const i32x4*)&qA[1][ln][slt];
#pragma unroll
            for (int ti = 0; ti < 2; ++ti) {
                int g = gp*2 + ti;
                const u8* bp = &ulds[(size_t)(((g*4 + a)*4 + kt)*2048) + l*16];
                i32x4 bh = *(const i32x4*)bp;
                i32x4 bl = *(const i32x4*)(bp + 1024);
                aP[ti][kt] = mfma8(hh, bh, aP[ti][kt]);
                aX[ti][kt] = mfma8(hl, bh, aX[ti][kt]);
                aX[ti][kt] = mfma8(hh, bl, aX[ti][kt]);
            }
        }
        // dequant (per-slice scale) -> z_lds
        float4 rv[4];
#pragma unroll
        for (int kt = 0; kt < 4; ++kt) rv[kt] = *(const float4*)&rmf[kt][lg*4];
#pragma unroll
        for (int ti = 0; ti < 2; ++ti) {
            int g = gp*2 + ti;
#pragma unroll
            for (int reg = 0; reg < 4; ++reg) {
                int row = lg*4 + reg;
                float zs = 0.f;
#pragma unroll
                for (int kt = 0; kt < 4; ++kt)
                    zs += (65536.f*(float)aP[ti][kt][reg] + 256.f*(float)aX[ti][kt][reg])
                          * ((const float*)&rv[kt])[reg];
                z_lds[g][row][a*16 + ln] = zs * cUw[ti];
            }
        }
        bar_lgk();   // z_lds ready

        // ---- (5) epilogue: gates for own (row, 2 units)
        const int mk = mask_l[r_e][s];
        float zg4[4][2];
#pragma unroll
        for (int g = 0; g < 4; ++g) {
            zg4[g][0] = z_lds[g][r_e][ul];
            zg4[g][1] = z_lds[g][r_e][ul + 16];
        }
        u16* mgs = mg_base + (size_t)s*1024;
#pragma unroll
        for (int m = 0; m < 2; ++m) {
            float zi = (float)(short)(m ? ((uint32_t)zA[0] >> 16) : ((uint32_t)zA[0] & 0xffffu))*INV_ZSCL + zg4[0][m];
            float zf = (float)(short)(m ? ((uint32_t)zA[1] >> 16) : ((uint32_t)zA[1] & 0xffffu))*INV_ZSCL + zg4[1][m];
            float zg = (float)(short)(m ? ((uint32_t)zA[2] >> 16) : ((uint32_t)zA[2] & 0xffffu))*INV_ZSCL + zg4[2][m];
            float zo = (float)(short)(m ? ((uint32_t)zA[3] >> 16) : ((uint32_t)zA[3] & 0xffffu))*INV_ZSCL + zg4[3][m];
            float ig = sigf(zi), fg = sigf(zf), og = sigf(zo);
            float gg = fmaxf(zg, 0.f);
            float cn = fg * c_[m] + ig * gg;
            float hn = og * fmaxf(cn, 0.f);
            if (!mk) { cn = c_[m]; hn = h_[m]; }
            c_[m] = cn; h_[m] = hn;
            mgs[m ? K1 : K0] = f2bf(hn);
        }
        zA = zn;
    }

    if (t0 + nt < 256) {
        size_t o = ((size_t)(lstm*128 + b0 + r_e))*256;
        c_state[o + K0] = c_[0]; c_state[o + K1] = c_[1];
        h_state[o + K0] = h_[0]; h_state[o + K1] = h_[1];
    }
}

// ---------------- attention + output head (verbatim)
__global__ __launch_bounds__(256) void attn_kernel(
    const u16* __restrict__ merged,
    const float* __restrict__ w_att, const float* __restrict__ b_att,
    const float* __restrict__ w_out, const float* __restrict__ b_out,
    float* __restrict__ out)
{
    const int b = blockIdx.x;
    const int tid = threadIdx.x;
    const int wv = tid >> 6;
    const int l = tid & 63;

    __shared__ float watt_s[1024];
    __shared__ float wout_s[1024];
    __shared__ float sc[256];
    __shared__ float red[8];

    for (int i = tid; i < 1024; i += 256) {
        watt_s[i] = w_att[i];
        wout_s[i] = w_out[i];
    }
    __syncthreads();

    const float batt = b_att[0];

    for (int tt = wv; tt < 256; tt += 4) {
        const u16* row = merged + ((size_t)b * 256 + tt) * 1024 + l * 16;
        uint4 q0 = *(const uint4*)(row);
        uint4 q1 = *(const uint4*)(row + 8);
        const float* wp = &watt_s[l * 16];
        uint32_t qa[8] = {q0.x, q0.y, q0.z, q0.w, q1.x, q1.y, q1.z, q1.w};
        float s = 0.f;
#pragma unroll
        for (int i = 0; i < 8; ++i) {
            s += bf2f((u16)(qa[i] & 0xffffu)) * wp[2 * i];
            s += bf2f((u16)(qa[i] >> 16)) * wp[2 * i + 1];
        }
#pragma unroll
        for (int o = 32; o > 0; o >>= 1) s += __shfl_xor(s, o);
        if (l == 0) sc[tt] = tanhf(s + batt);
    }
    __syncthreads();

    float v = sc[tid];
    float mx = v;
#pragma unroll
    for (int o = 32; o > 0; o >>= 1) mx = fmaxf(mx, __shfl_xor(mx, o));
    if (l == 0) red[wv] = mx;
    __syncthreads();
    mx = fmaxf(fmaxf(red[0], red[1]), fmaxf(red[2], red[3]));
    float p = __expf(v - mx);
    float sm = p;
#pragma unroll
    for (int o = 32; o > 0; o >>= 1) sm += __shfl_xor(sm, o);
    if (l == 0) red[4 + wv] = sm;
    __syncthreads();
    sm = red[4] + red[5] + red[6] + red[7];
    p /= sm;
    sc[tid] = p;
    __syncthreads();

    const int d0 = tid * 4;
    float a0 = 0.f, a1 = 0.f, a2 = 0.f, a3 = 0.f;
    for (int t = 0; t < 256; ++t) {
        float pp = sc[t];
        const u16* mp = merged + ((size_t)b * 256 + t) * 1024 + d0;
        ushort4 q = *(const ushort4*)mp;
        a0 += pp * bf2f(q.x);
        a1 += pp * bf2f(q.y);
        a2 += pp * bf2f(q.z);
        a3 += pp * bf2f(q.w);
    }
    float part = a0 * wout_s[d0] + a1 * wout_s[d0 + 1] + a2 * wout_s[d0 + 2] + a3 * wout_s[d0 + 3];
#pragma unroll
    for (int o = 32; o > 0; o >>= 1) part += __shfl_xor(part, o);
    __syncthreads();
    if (l == 0) red[wv] = part;
    __syncthreads();
    if (tid == 0) {
        float tot = red[0] + red[1] + red[2] + red[3] + b_out[0];
        out[b] = 1.0f / (1.0f + __expf(-tot));
    }
}

extern "C" void kernel_launch(void* const* d_in, const int* in_sizes, int n_in,
                              void* d_out, int out_size, void* d_ws, size_t ws_size,
                              hipStream_t stream) {
    (void)in_sizes; (void)n_in; (void)out_size;
    const float* x[4]; const float* W[4]; const float* U[4]; const float* bb[4];
    for (int i = 0; i < 4; ++i) {
        x[i]  = (const float*)d_in[4 * i + 0];
        W[i]  = (const float*)d_in[4 * i + 1];
        U[i]  = (const float*)d_in[4 * i + 2];
        bb[i] = (const float*)d_in[4 * i + 3];
    }
    const float* w_att = (const float*)d_in[16];
    const float* b_att = (const float*)d_in[17];
    const float* w_out = (const float*)d_in[18];
    const float* b_out = (const float*)d_in[19];

    u8* base = (u8*)d_ws;
    size_t off = 0;
    auto alloc = [&](size_t n) { u8* p = base + off; off += (n + 255) & ~(size_t)255; return p; };
    u16*   merged  = (u16*)  alloc(67108864);        // [128][256][1024] bf16
    u8*    Upk4    =         alloc(2097152);         // i8 hi/lo, colsplit-slice layout
    u16*   Wbh     = (u16*)  alloc(786432);
    u16*   Wbl     = (u16*)  alloc(786432);
    float* Uscale  = (float*)alloc(16384);
    u8*    maskb   =         alloc(131072);
    float* c_state = (float*)alloc(524288);
    float* h_state = (float*)alloc(524288);
    u8*    exbuf   =         alloc(1048576);         // 32 groups x 2 bufs x 4 x 4KB
    int*   cnt     = (int*)  alloc(4096);            // 32 counters, 128B-strided
    size_t fixed = off;

    int nt = 256;                                     // zx chunk = nt MB; adapt to ws_size
    while (nt > 16 && fixed + (size_t)nt * 1048576 > ws_size) nt >>= 1;
    short* zxg = (short*)alloc((size_t)nt * 1048576);

    uscale_kernel<<<dim3(16),   dim3(256), 0, stream>>>(U[0], U[1], U[2], U[3], Uscale);
    upack_kernel <<<dim3(2048), dim3(256), 0, stream>>>(U[0], U[1], U[2], U[3], Uscale, Upk4);
    wpair_kernel <<<dim3(1536), dim3(256), 0, stream>>>(W[0], W[1], W[2], W[3], Wbh, Wbl);

    for (int t0 = 0; t0 < 256; t0 += nt) {
        zx_gemm_kernel<<<dim3(512), dim3(512), 0, stream>>>(
            x[0], x[1], x[2], x[3], bb[0], bb[1], bb[2], bb[3],
            Wbh, Wbl, zxg, maskb, t0, nt);
        zero_cnt_kernel<<<dim3(1), dim3(64), 0, stream>>>(cnt);
        lstm_rec_kernel<<<dim3(128), dim3(512), 0, stream>>>(
            Upk4, zxg, maskb, Uscale, c_state, h_state, merged, exbuf, cnt, t0, nt);
    }

    attn_kernel<<<dim3(128), dim3(256), 0, stream>>>(
        merged, w_att, b_att, w_out, b_out, (float*)d_out);
}